// Round 13
// baseline (272.293 us; speedup 1.0000x reference)
//
#include <hip/hip_runtime.h>
#include <hip/hip_bf16.h>

#define NR  8192      // rows per view
#define M   16384     // 2*NR concatenated
#define TB  32768     // 256 cols * 128 B (one fp8 Y chunk tile)

constexpr float INV_T   = 2.5f;                  // 1/0.4
constexpr float SCALE_S = 1.89914134f;           // sqrt(2.5*log2(e)); s^2=2.5*log2e
constexpr float E_REFL  = 12.182493960703473f;   // exp(2.5)
constexpr unsigned UNIT_E8M0 = 0x7F7F7F7Fu;      // e8m0 scale = 2^0 in all bytes

typedef int   i32x4 __attribute__((ext_vector_type(4)));
typedef int   i32x8 __attribute__((ext_vector_type(8)));
typedef float f32x4 __attribute__((ext_vector_type(4)));

typedef const __attribute__((address_space(1))) unsigned int* gas_u32;
typedef __attribute__((address_space(3))) unsigned int*       las_u32;

__device__ __forceinline__ float fexp2(float x) {
#if __has_builtin(__builtin_amdgcn_exp2f)
    return __builtin_amdgcn_exp2f(x);
#else
    return exp2f(x);
#endif
}

// ---------------------------------------------------------------------------
// Kernel 1: L2-normalize rows; store fp8(e4m3) Z = [z1n; z2n] PRE-SCALED by
// SCALE_S (so the MX-MFMA output is directly the exp2 argument); fp32 cross
// dot; zero the rowsum array R.
// ---------------------------------------------------------------------------
__global__ __launch_bounds__(256) void norm_kernel(
    const float* __restrict__ outp, const float* __restrict__ augp,
    unsigned char* __restrict__ Zf8, float* __restrict__ R,
    float* __restrict__ posdot)
{
    int gt = blockIdx.x * 256 + threadIdx.x;
    if (gt < M) R[gt] = 0.0f;

    const int w    = threadIdx.x >> 6;
    const int lane = threadIdx.x & 63;
    const int row  = blockIdx.x * 4 + w;

    float2 a = *(const float2*)(outp + row * 128 + lane * 2);
    float2 b = *(const float2*)(augp + row * 128 + lane * 2);

    float ssa = a.x * a.x + a.y * a.y;
    float ssb = b.x * b.x + b.y * b.y;
    #pragma unroll
    for (int m = 1; m < 64; m <<= 1) {
        ssa += __shfl_xor(ssa, m);
        ssb += __shfl_xor(ssb, m);
    }
    float inva = 1.0f / fmaxf(sqrtf(ssa), 1e-12f);
    float invb = 1.0f / fmaxf(sqrtf(ssb), 1e-12f);

    float xa0 = a.x * inva, xa1 = a.y * inva;   // unit-normalized (fp32)
    float xb0 = b.x * invb, xb1 = b.y * invb;

    unsigned int pa = __builtin_amdgcn_cvt_pk_fp8_f32(xa0 * SCALE_S, xa1 * SCALE_S, 0, false);
    unsigned int pb = __builtin_amdgcn_cvt_pk_fp8_f32(xb0 * SCALE_S, xb1 * SCALE_S, 0, false);
    *(unsigned short*)(Zf8 + (size_t)row * 128 + lane * 2)        = (unsigned short)pa;
    *(unsigned short*)(Zf8 + (size_t)(NR + row) * 128 + lane * 2) = (unsigned short)pb;

    float d = xa0 * xb0 + xa1 * xb1;   // positive-pair dot stays fp32-exact
    #pragma unroll
    for (int m = 1; m < 64; m <<= 1) d += __shfl_xor(d, m);
    if (lane == 0) posdot[row] = d;
}

// ---------------------------------------------------------------------------
// Kernel 2: row sums of exp2(Zs Zs^T) via MX-fp8 K=128 MFMA — SINGLE-SHOT
// blocks, ONE barrier, zero inner synchronization.
// Grid (64 col-chunks, 64 row-strips) = 4096 blocks.  Per block: Y chunk =
// 256 cols (32 KB fp8) staged ONCE via swizzled global_load_lds -> one
// __syncthreads -> pure compute: per wave 16 ct x {2 ds_read_b128 -> b8 ->
// 4 MFMA (rt) -> 16 exp2 -> 16 adds}, ~3 us, no barriers.  5 resident
// blocks/CU (LDS 160/32; VGPR ~70 at (256,4) cap) = 20 waves/CU whose
// start/finish staggering de-phases the MFMA / trans-exp2 / LDS pipes —
// the per-subtile barrier lockstep of R12 (wall = serial pipe sum) is gone.
// A-frags (full K=128, 32 B/lane) direct from L2.  id%8 pins ch%8 to an
// XCD: Y working set 256 KB + Z 2 MB fit the 4 MB XCD L2.
// ---------------------------------------------------------------------------
__global__ __launch_bounds__(256, 4) void gram_kernel(
    const unsigned char* __restrict__ Zf8, float* __restrict__ R)
{
    __shared__ char Ys[TB];   // 32 KB

    const int tid  = threadIdx.x;
    const int w    = tid >> 6;       // 0..3
    const int lane = tid & 63;
    const int l16  = lane & 15;
    const int lg   = lane >> 4;      // 0..3 (32-byte k-chunk)
    const int ch   = blockIdx.x;     // 0..63 (256 cols each)
    const int rb   = blockIdx.y;     // 0..63 (256 rows each)

    const char* Zb = (const char*)Zf8;
    const char* Xg = Zb + (size_t)rb * 32768;     // 256 rows * 128 B
    const char* Yg = Zb + (size_t)ch * 32768;     // 256 cols * 128 B

    // stage Y tile (32 KB): LDS[linear] = G[swz(linear)]; swz XORs byte bits
    // 4..6 with the row index (byte>>7)&7 — involution, matches read side.
    #pragma unroll
    for (int it = 0; it < 8; ++it) {
        int off = w * 8192 + it * 1024 + lane * 16;
        int swz = off ^ (((off >> 7) & 7) << 4);
        __builtin_amdgcn_global_load_lds((gas_u32)(Yg + swz),
                                         (las_u32)(Ys + w * 8192 + it * 1024),
                                         16, 0, 0);
    }

    // A fragments: 64 rows per wave, full K=128 (32 B/lane), direct from L2
    i32x8 afrag[4];
    #pragma unroll
    for (int rt = 0; rt < 4; ++rt)
        afrag[rt] = *(const i32x8*)(Xg + (w * 64 + rt * 16 + l16) * 128 + lg * 32);

    __syncthreads();   // the ONLY barrier: Y tile staged

    f32x4 rs[4];
    #pragma unroll
    for (int rt = 0; rt < 4; ++rt) rs[rt] = (f32x4){0.f, 0.f, 0.f, 0.f};
    const f32x4 zero4 = (f32x4){0.f, 0.f, 0.f, 0.f};

    // lane-constant swizzled LDS offsets; ct contributes bits >= 11 only
    const int key   = (l16 & 7) << 4;
    const int lbase = l16 * 128 + lg * 32;
    const int addrA = lbase ^ key;
    const int addrB = (lbase + 16) ^ key;

    #pragma unroll
    for (int ct = 0; ct < 16; ++ct) {
        i32x4 lo = *(const i32x4*)(Ys + ct * 2048 + addrA);
        i32x4 hi = *(const i32x4*)(Ys + ct * 2048 + addrB);
        i32x8 b8 = {lo[0], lo[1], lo[2], lo[3], hi[0], hi[1], hi[2], hi[3]};
        #pragma unroll
        for (int rt = 0; rt < 4; ++rt) {
            f32x4 d = __builtin_amdgcn_mfma_scale_f32_16x16x128_f8f6f4(
                afrag[rt], b8, zero4,
                0 /*fmtA=fp8*/, 0 /*fmtB=fp8*/,
                0, UNIT_E8M0, 0, UNIT_E8M0);
            f32x4 e;
            e[0] = fexp2(d[0]); e[1] = fexp2(d[1]);
            e[2] = fexp2(d[2]); e[3] = fexp2(d[3]);
            rs[rt] += e;
        }
    }

    // reduce row sums across the 16 lanes holding one row's columns
    #pragma unroll
    for (int rt = 0; rt < 4; ++rt)
        #pragma unroll
        for (int q = 0; q < 4; ++q) {
            float v = rs[rt][q];
            v += __shfl_xor(v, 1);  v += __shfl_xor(v, 2);
            v += __shfl_xor(v, 4);  v += __shfl_xor(v, 8);
            if (l16 == 0)
                atomicAdd(&R[rb * 256 + w * 64 + rt * 16 + lg * 4 + q], v);
        }
}

// ---------------------------------------------------------------------------
// Kernel 3: loss = mean_i [ -dot_i/tau + 0.5(log(R_i - E) + log(R_{NR+i} - E)) ]
// ---------------------------------------------------------------------------
__global__ __launch_bounds__(256) void final_kernel(
    const float* __restrict__ R, const float* __restrict__ posdot,
    float* __restrict__ outv)
{
    float local = 0.0f;
    for (int i = threadIdx.x; i < NR; i += 256) {
        float d1 = R[i]      - E_REFL;
        float d2 = R[NR + i] - E_REFL;
        local += -posdot[i] * INV_T + 0.5f * (logf(d1) + logf(d2));
    }
    __shared__ float red[256];
    red[threadIdx.x] = local;
    __syncthreads();
    for (int s = 128; s > 0; s >>= 1) {
        if ((int)threadIdx.x < s) red[threadIdx.x] += red[threadIdx.x + s];
        __syncthreads();
    }
    if (threadIdx.x == 0) outv[0] = red[0] * (1.0f / NR);
}

// ---------------------------------------------------------------------------
extern "C" void kernel_launch(void* const* d_in, const int* in_sizes, int n_in,
                              void* d_out, int out_size, void* d_ws, size_t ws_size,
                              hipStream_t stream) {
    const float* outp = (const float*)d_in[0];
    const float* augp = (const float*)d_in[1];

    char* ws = (char*)d_ws;
    unsigned char* Zf8 = (unsigned char*)ws;                  // 2 MB fp8 [16384][128]
    float* R      = (float*)(ws + 2097152);                   // 16384 f32 row sums
    float* posdot = (float*)(ws + 2097152 + 65536);           // 8192 f32
    float* outf   = (float*)d_out;

    hipLaunchKernelGGL(norm_kernel, dim3(2048), dim3(256), 0, stream,
                       outp, augp, Zf8, R, posdot);

    hipLaunchKernelGGL(gram_kernel, dim3(64, 64), dim3(256), 0, stream,
                       Zf8, R);

    hipLaunchKernelGGL(final_kernel, dim3(1), dim3(256), 0, stream,
                       R, posdot, outf);
}

// Round 14
// 73.524 us; speedup vs baseline: 3.7035x; 3.7035x over previous
//
#include <hip/hip_runtime.h>
#include <hip/hip_bf16.h>

#define NR  8192      // rows per view
#define M   16384     // 2*NR concatenated
#define TB  32768     // 256 cols * 128 B (one fp8 Y chunk tile)

constexpr float INV_T   = 2.5f;                  // 1/0.4
constexpr float SCALE_S = 1.89914134f;           // sqrt(2.5*log2(e)); s^2=2.5*log2e
constexpr float E_REFL  = 12.182493960703473f;   // exp(2.5)
constexpr unsigned UNIT_E8M0 = 0x7F7F7F7Fu;      // e8m0 scale = 2^0 in all bytes

typedef int   i32x4 __attribute__((ext_vector_type(4)));
typedef int   i32x8 __attribute__((ext_vector_type(8)));
typedef float f32x4 __attribute__((ext_vector_type(4)));

typedef const __attribute__((address_space(1))) unsigned int* gas_u32;
typedef __attribute__((address_space(3))) unsigned int*       las_u32;

__device__ __forceinline__ float fexp2(float x) {
#if __has_builtin(__builtin_amdgcn_exp2f)
    return __builtin_amdgcn_exp2f(x);
#else
    return exp2f(x);
#endif
}

// ---------------------------------------------------------------------------
// Kernel 1: L2-normalize rows; store fp8(e4m3) Z = [z1n; z2n] PRE-SCALED by
// SCALE_S (so the MX-MFMA output is directly the exp2 argument); fp32 cross
// dot; zero the rowsum array R.
// ---------------------------------------------------------------------------
__global__ __launch_bounds__(256) void norm_kernel(
    const float* __restrict__ outp, const float* __restrict__ augp,
    unsigned char* __restrict__ Zf8, float* __restrict__ R,
    float* __restrict__ posdot)
{
    int gt = blockIdx.x * 256 + threadIdx.x;
    if (gt < M) R[gt] = 0.0f;

    const int w    = threadIdx.x >> 6;
    const int lane = threadIdx.x & 63;
    const int row  = blockIdx.x * 4 + w;

    float2 a = *(const float2*)(outp + row * 128 + lane * 2);
    float2 b = *(const float2*)(augp + row * 128 + lane * 2);

    float ssa = a.x * a.x + a.y * a.y;
    float ssb = b.x * b.x + b.y * b.y;
    #pragma unroll
    for (int m = 1; m < 64; m <<= 1) {
        ssa += __shfl_xor(ssa, m);
        ssb += __shfl_xor(ssb, m);
    }
    float inva = 1.0f / fmaxf(sqrtf(ssa), 1e-12f);
    float invb = 1.0f / fmaxf(sqrtf(ssb), 1e-12f);

    float xa0 = a.x * inva, xa1 = a.y * inva;   // unit-normalized (fp32)
    float xb0 = b.x * invb, xb1 = b.y * invb;

    unsigned int pa = __builtin_amdgcn_cvt_pk_fp8_f32(xa0 * SCALE_S, xa1 * SCALE_S, 0, false);
    unsigned int pb = __builtin_amdgcn_cvt_pk_fp8_f32(xb0 * SCALE_S, xb1 * SCALE_S, 0, false);
    *(unsigned short*)(Zf8 + (size_t)row * 128 + lane * 2)        = (unsigned short)pa;
    *(unsigned short*)(Zf8 + (size_t)(NR + row) * 128 + lane * 2) = (unsigned short)pb;

    float d = xa0 * xb0 + xa1 * xb1;   // positive-pair dot stays fp32-exact
    #pragma unroll
    for (int m = 1; m < 64; m <<= 1) d += __shfl_xor(d, m);
    if (lane == 0) posdot[row] = d;
}

// ---------------------------------------------------------------------------
// Kernel 2: row sums of exp2(Zs Zs^T) via MX-fp8 K=128 MFMA — single-shot
// blocks, ONE barrier, bounded register pressure.
// Grid (64 col-chunks, 64 row-strips) = 4096 blocks.  Per block: Y chunk =
// 256 cols (32 KB fp8) staged ONCE via swizzled global_load_lds -> one
// __syncthreads -> compute with NO further syncs.  The compute loop is
// `#pragma unroll 1` over 4 col-blocks (inner unroll 4 ct) — R13's full
// 16-ct unroll let the scheduler hoist all 32 ds_read_b128 (128 VGPRs of
// B-operands) past the MFMAs, blowing the 128-VGPR cap and spilling accs
// to scratch (655 MB FETCH + 442 MB WRITE).  This bounds live B-operands
// to 4 iterations (R12's proven 44-VGPR pattern).
// 4-5 resident blocks/CU; block start/finish staggering de-phases the
// MFMA / trans-exp2 / LDS pipes without barrier lockstep.
// A-frags (full K=128, 32 B/lane) direct from L2.  id%8 pins ch%8 to an
// XCD: Y working set + Z 2 MB fit the 4 MB XCD L2.
// ---------------------------------------------------------------------------
__global__ __launch_bounds__(256, 4) void gram_kernel(
    const unsigned char* __restrict__ Zf8, float* __restrict__ R)
{
    __shared__ char Ys[TB];   // 32 KB

    const int tid  = threadIdx.x;
    const int w    = tid >> 6;       // 0..3
    const int lane = tid & 63;
    const int l16  = lane & 15;
    const int lg   = lane >> 4;      // 0..3 (32-byte k-chunk)
    const int ch   = blockIdx.x;     // 0..63 (256 cols each)
    const int rb   = blockIdx.y;     // 0..63 (256 rows each)

    const char* Zb = (const char*)Zf8;
    const char* Xg = Zb + (size_t)rb * 32768;     // 256 rows * 128 B
    const char* Yg = Zb + (size_t)ch * 32768;     // 256 cols * 128 B

    // stage Y tile (32 KB): LDS[linear] = G[swz(linear)]; swz XORs byte bits
    // 4..6 with the row index (byte>>7)&7 — involution, matches read side.
    #pragma unroll
    for (int it = 0; it < 8; ++it) {
        int off = w * 8192 + it * 1024 + lane * 16;
        int swz = off ^ (((off >> 7) & 7) << 4);
        __builtin_amdgcn_global_load_lds((gas_u32)(Yg + swz),
                                         (las_u32)(Ys + w * 8192 + it * 1024),
                                         16, 0, 0);
    }

    // A fragments: 64 rows per wave, full K=128 (32 B/lane), direct from L2
    i32x8 afrag[4];
    #pragma unroll
    for (int rt = 0; rt < 4; ++rt)
        afrag[rt] = *(const i32x8*)(Xg + (w * 64 + rt * 16 + l16) * 128 + lg * 32);

    __syncthreads();   // the ONLY barrier: Y tile staged

    f32x4 rs[4];
    #pragma unroll
    for (int rt = 0; rt < 4; ++rt) rs[rt] = (f32x4){0.f, 0.f, 0.f, 0.f};
    const f32x4 zero4 = (f32x4){0.f, 0.f, 0.f, 0.f};

    // lane-constant swizzled LDS offsets; ct contributes bits >= 11 only
    const int key   = (l16 & 7) << 4;
    const int lbase = l16 * 128 + lg * 32;
    const int addrA = lbase ^ key;
    const int addrB = (lbase + 16) ^ key;

    #pragma unroll 1
    for (int cb = 0; cb < 4; ++cb) {
        const char* base = Ys + cb * 8192;
        #pragma unroll
        for (int ct = 0; ct < 4; ++ct) {
            i32x4 lo = *(const i32x4*)(base + ct * 2048 + addrA);
            i32x4 hi = *(const i32x4*)(base + ct * 2048 + addrB);
            i32x8 b8 = {lo[0], lo[1], lo[2], lo[3], hi[0], hi[1], hi[2], hi[3]};
            #pragma unroll
            for (int rt = 0; rt < 4; ++rt) {
                f32x4 d = __builtin_amdgcn_mfma_scale_f32_16x16x128_f8f6f4(
                    afrag[rt], b8, zero4,
                    0 /*fmtA=fp8*/, 0 /*fmtB=fp8*/,
                    0, UNIT_E8M0, 0, UNIT_E8M0);
                f32x4 e;
                e[0] = fexp2(d[0]); e[1] = fexp2(d[1]);
                e[2] = fexp2(d[2]); e[3] = fexp2(d[3]);
                rs[rt] += e;
            }
        }
    }

    // reduce row sums across the 16 lanes holding one row's columns
    #pragma unroll
    for (int rt = 0; rt < 4; ++rt)
        #pragma unroll
        for (int q = 0; q < 4; ++q) {
            float v = rs[rt][q];
            v += __shfl_xor(v, 1);  v += __shfl_xor(v, 2);
            v += __shfl_xor(v, 4);  v += __shfl_xor(v, 8);
            if (l16 == 0)
                atomicAdd(&R[rb * 256 + w * 64 + rt * 16 + lg * 4 + q], v);
        }
}

// ---------------------------------------------------------------------------
// Kernel 3: loss = mean_i [ -dot_i/tau + 0.5(log(R_i - E) + log(R_{NR+i} - E)) ]
// ---------------------------------------------------------------------------
__global__ __launch_bounds__(256) void final_kernel(
    const float* __restrict__ R, const float* __restrict__ posdot,
    float* __restrict__ outv)
{
    float local = 0.0f;
    for (int i = threadIdx.x; i < NR; i += 256) {
        float d1 = R[i]      - E_REFL;
        float d2 = R[NR + i] - E_REFL;
        local += -posdot[i] * INV_T + 0.5f * (logf(d1) + logf(d2));
    }
    __shared__ float red[256];
    red[threadIdx.x] = local;
    __syncthreads();
    for (int s = 128; s > 0; s >>= 1) {
        if ((int)threadIdx.x < s) red[threadIdx.x] += red[threadIdx.x + s];
        __syncthreads();
    }
    if (threadIdx.x == 0) outv[0] = red[0] * (1.0f / NR);
}

// ---------------------------------------------------------------------------
extern "C" void kernel_launch(void* const* d_in, const int* in_sizes, int n_in,
                              void* d_out, int out_size, void* d_ws, size_t ws_size,
                              hipStream_t stream) {
    const float* outp = (const float*)d_in[0];
    const float* augp = (const float*)d_in[1];

    char* ws = (char*)d_ws;
    unsigned char* Zf8 = (unsigned char*)ws;                  // 2 MB fp8 [16384][128]
    float* R      = (float*)(ws + 2097152);                   // 16384 f32 row sums
    float* posdot = (float*)(ws + 2097152 + 65536);           // 8192 f32
    float* outf   = (float*)d_out;

    hipLaunchKernelGGL(norm_kernel, dim3(2048), dim3(256), 0, stream,
                       outp, augp, Zf8, R, posdot);

    hipLaunchKernelGGL(gram_kernel, dim3(64, 64), dim3(256), 0, stream,
                       Zf8, R);

    hipLaunchKernelGGL(final_kernel, dim3(1), dim3(256), 0, stream,
                       R, posdot, outf);
}

// Round 15
// 72.716 us; speedup vs baseline: 3.7446x; 1.0111x over previous
//
#include <hip/hip_runtime.h>
#include <hip/hip_bf16.h>

#define NR  8192      // rows per view
#define M   16384     // 2*NR concatenated
#define WSUB 4096     // 32 cols * 128 B (one wave-private fp8 Y sub-tile)

constexpr float INV_T   = 2.5f;                  // 1/0.4
constexpr float SCALE_S = 1.89914134f;           // sqrt(2.5*log2(e)); s^2=2.5*log2e
constexpr float E_REFL  = 12.182493960703473f;   // exp(2.5)
constexpr unsigned UNIT_E8M0 = 0x7F7F7F7Fu;      // e8m0 scale = 2^0 in all bytes

typedef int   i32x4 __attribute__((ext_vector_type(4)));
typedef int   i32x8 __attribute__((ext_vector_type(8)));
typedef float f32x4 __attribute__((ext_vector_type(4)));

typedef const __attribute__((address_space(1))) unsigned int* gas_u32;
typedef __attribute__((address_space(3))) unsigned int*       las_u32;

__device__ __forceinline__ float fexp2(float x) {
#if __has_builtin(__builtin_amdgcn_exp2f)
    return __builtin_amdgcn_exp2f(x);
#else
    return exp2f(x);
#endif
}

// Stage one wave-private 32-col (4 KB) fp8 sub-tile global->LDS:
// 4 x global_load_lds(16B) per lane-group pass.  LDS dest linear; global
// src XOR-pre-swizzled (involution on byte bits 4..6 keyed by row&7 =
// bits 7..9) so the swizzled 16B fragment reads are low-conflict.
__device__ __forceinline__ void stage_wave(const char* __restrict__ gsrc,
                                           char* lds, int lane) {
    #pragma unroll
    for (int it = 0; it < 4; ++it) {
        int off = it * 1024 + lane * 16;
        int swz = off ^ (((off >> 7) & 7) << 4);
        __builtin_amdgcn_global_load_lds((gas_u32)(gsrc + swz),
                                         (las_u32)(lds + it * 1024),
                                         16, 0, 0);
    }
}

// ---------------------------------------------------------------------------
// Kernel 1: L2-normalize rows; store fp8(e4m3) Z = [z1n; z2n] PRE-SCALED by
// SCALE_S (so the MX-MFMA output is directly the exp2 argument); fp32 cross
// dot; zero the rowsum array R.
// ---------------------------------------------------------------------------
__global__ __launch_bounds__(256) void norm_kernel(
    const float* __restrict__ outp, const float* __restrict__ augp,
    unsigned char* __restrict__ Zf8, float* __restrict__ R,
    float* __restrict__ posdot)
{
    int gt = blockIdx.x * 256 + threadIdx.x;
    if (gt < M) R[gt] = 0.0f;

    const int w    = threadIdx.x >> 6;
    const int lane = threadIdx.x & 63;
    const int row  = blockIdx.x * 4 + w;

    float2 a = *(const float2*)(outp + row * 128 + lane * 2);
    float2 b = *(const float2*)(augp + row * 128 + lane * 2);

    float ssa = a.x * a.x + a.y * a.y;
    float ssb = b.x * b.x + b.y * b.y;
    #pragma unroll
    for (int m = 1; m < 64; m <<= 1) {
        ssa += __shfl_xor(ssa, m);
        ssb += __shfl_xor(ssb, m);
    }
    float inva = 1.0f / fmaxf(sqrtf(ssa), 1e-12f);
    float invb = 1.0f / fmaxf(sqrtf(ssb), 1e-12f);

    float xa0 = a.x * inva, xa1 = a.y * inva;   // unit-normalized (fp32)
    float xb0 = b.x * invb, xb1 = b.y * invb;

    unsigned int pa = __builtin_amdgcn_cvt_pk_fp8_f32(xa0 * SCALE_S, xa1 * SCALE_S, 0, false);
    unsigned int pb = __builtin_amdgcn_cvt_pk_fp8_f32(xb0 * SCALE_S, xb1 * SCALE_S, 0, false);
    *(unsigned short*)(Zf8 + (size_t)row * 128 + lane * 2)        = (unsigned short)pa;
    *(unsigned short*)(Zf8 + (size_t)(NR + row) * 128 + lane * 2) = (unsigned short)pb;

    float d = xa0 * xb0 + xa1 * xb1;   // positive-pair dot stays fp32-exact
    #pragma unroll
    for (int m = 1; m < 64; m <<= 1) d += __shfl_xor(d, m);
    if (lane == 0) posdot[row] = d;
}

// ---------------------------------------------------------------------------
// Kernel 2: row sums of exp2(Zs Zs^T) via MX-fp8 K=128 MFMA — ZERO BARRIERS,
// fully self-paced waves.  Every structure so far (R6-R14) kept block-level
// phase coupling (shared LDS buffers -> common stage/drain points), and the
// wall equalled the SERIAL pipe sum (MFMA 14.7 + VALU ~20 + LDS 10 us/SIMD)
// instead of their max.  Here each wave owns a PRIVATE 2 x 4 KB LDS ring and
// paces itself with its own counted vmcnt — no __syncthreads after launch.
// Waves drift apart, so each SIMD holds waves in different phases (MFMA /
// trans-exp2 / ds_read) that overlap on disjoint pipes.
// Grid (32 col-chunks, 64 row-strips) = 2048 blocks; 32 KB LDS/block -> 5
// resident blocks/CU = 20 waves.  Wave owns 64 rows x 512 cols: afrag[4]
// (full K=128, 32 B/lane, one-time L2 read); 16 wave-subtiles of 32 cols
// (4 KB), double-buffered; per subtile: issue stage(s+1) (4 gload_lds),
// compute 2 ct x {2 swizzled ds_read_b128 -> b8 -> 4 MFMA -> 16 exp2 ->
// adds} (~600 cyc, covers L2 latency), trailing s_waitcnt vmcnt(0).
// Staging L2 traffic is 4x block-shared (each wave stages its own copy):
// ~512 MB total, ~42% of per-XCD L2 BW — async, affordable.
// id%8 = ch%8 pins 4 chunks/XCD: Y set 256 KB + Z 2 MB fit the 4 MB L2.
// ---------------------------------------------------------------------------
__global__ __launch_bounds__(256, 4) void gram_kernel(
    const unsigned char* __restrict__ Zf8, float* __restrict__ R)
{
    __shared__ char buf[4][2][WSUB];   // 4 waves x 2 x 4 KB = 32 KB

    const int tid  = threadIdx.x;
    const int w    = tid >> 6;       // 0..3
    const int lane = tid & 63;
    const int l16  = lane & 15;
    const int lg   = lane >> 4;      // 0..3 (32-byte k-chunk)
    const int ch   = blockIdx.x;     // 0..31 (512 cols each)
    const int rb   = blockIdx.y;     // 0..63 (256 rows each)

    const char* Zb = (const char*)Zf8;
    const char* Xg = Zb + (size_t)rb * 32768;     // 256 rows * 128 B
    const char* Yg = Zb + (size_t)ch * 65536;     // 512 cols * 128 B

    // A fragments: 64 rows per wave, full K=128 (32 B/lane), one-time read
    i32x8 afrag[4];
    #pragma unroll
    for (int rt = 0; rt < 4; ++rt)
        afrag[rt] = *(const i32x8*)(Xg + (w * 64 + rt * 16 + l16) * 128 + lg * 32);

    char* myb0 = (char*)buf[w][0];
    char* myb1 = (char*)buf[w][1];

    stage_wave(Yg, myb0, lane);
    asm volatile("s_waitcnt vmcnt(0)" ::: "memory");   // afrag + subtile 0
    __builtin_amdgcn_sched_barrier(0);

    f32x4 rs[4];
    #pragma unroll
    for (int rt = 0; rt < 4; ++rt) rs[rt] = (f32x4){0.f, 0.f, 0.f, 0.f};
    const f32x4 zero4 = (f32x4){0.f, 0.f, 0.f, 0.f};

    // lane-constant swizzled LDS offsets; ct contributes bit 11 only
    const int key   = (l16 & 7) << 4;
    const int lbase = l16 * 128 + lg * 32;
    const int addrA = lbase ^ key;
    const int addrB = (lbase + 16) ^ key;

    #pragma unroll 1
    for (int s = 0; s < 16; ++s) {
        char* cur = (s & 1) ? myb1 : myb0;
        char* nxt = (s & 1) ? myb0 : myb1;
        if (s + 1 < 16)
            stage_wave(Yg + (size_t)(s + 1) * WSUB, nxt, lane);

        #pragma unroll
        for (int ct = 0; ct < 2; ++ct) {
            i32x4 lo = *(const i32x4*)(cur + ct * 2048 + addrA);
            i32x4 hi = *(const i32x4*)(cur + ct * 2048 + addrB);
            i32x8 b8 = {lo[0], lo[1], lo[2], lo[3], hi[0], hi[1], hi[2], hi[3]};
            #pragma unroll
            for (int rt = 0; rt < 4; ++rt) {
                f32x4 d = __builtin_amdgcn_mfma_scale_f32_16x16x128_f8f6f4(
                    afrag[rt], b8, zero4,
                    0 /*fmtA=fp8*/, 0 /*fmtB=fp8*/,
                    0, UNIT_E8M0, 0, UNIT_E8M0);
                f32x4 e;
                e[0] = fexp2(d[0]); e[1] = fexp2(d[1]);
                e[2] = fexp2(d[2]); e[3] = fexp2(d[3]);
                rs[rt] += e;
            }
        }

        // wait MY stage(s+1) (landed during the ~600-cyc compute); no
        // cross-wave sync — wave-private buffer, self-paced.
        asm volatile("s_waitcnt vmcnt(0)" ::: "memory");
        __builtin_amdgcn_sched_barrier(0);
    }

    // reduce row sums across the 16 lanes holding one row's columns
    #pragma unroll
    for (int rt = 0; rt < 4; ++rt)
        #pragma unroll
        for (int q = 0; q < 4; ++q) {
            float v = rs[rt][q];
            v += __shfl_xor(v, 1);  v += __shfl_xor(v, 2);
            v += __shfl_xor(v, 4);  v += __shfl_xor(v, 8);
            if (l16 == 0)
                atomicAdd(&R[rb * 256 + w * 64 + rt * 16 + lg * 4 + q], v);
        }
}

// ---------------------------------------------------------------------------
// Kernel 3: loss = mean_i [ -dot_i/tau + 0.5(log(R_i - E) + log(R_{NR+i} - E)) ]
// ---------------------------------------------------------------------------
__global__ __launch_bounds__(256) void final_kernel(
    const float* __restrict__ R, const float* __restrict__ posdot,
    float* __restrict__ outv)
{
    float local = 0.0f;
    for (int i = threadIdx.x; i < NR; i += 256) {
        float d1 = R[i]      - E_REFL;
        float d2 = R[NR + i] - E_REFL;
        local += -posdot[i] * INV_T + 0.5f * (logf(d1) + logf(d2));
    }
    __shared__ float red[256];
    red[threadIdx.x] = local;
    __syncthreads();
    for (int s = 128; s > 0; s >>= 1) {
        if ((int)threadIdx.x < s) red[threadIdx.x] += red[threadIdx.x + s];
        __syncthreads();
    }
    if (threadIdx.x == 0) outv[0] = red[0] * (1.0f / NR);
}

// ---------------------------------------------------------------------------
extern "C" void kernel_launch(void* const* d_in, const int* in_sizes, int n_in,
                              void* d_out, int out_size, void* d_ws, size_t ws_size,
                              hipStream_t stream) {
    const float* outp = (const float*)d_in[0];
    const float* augp = (const float*)d_in[1];

    char* ws = (char*)d_ws;
    unsigned char* Zf8 = (unsigned char*)ws;                  // 2 MB fp8 [16384][128]
    float* R      = (float*)(ws + 2097152);                   // 16384 f32 row sums
    float* posdot = (float*)(ws + 2097152 + 65536);           // 8192 f32
    float* outf   = (float*)d_out;

    hipLaunchKernelGGL(norm_kernel, dim3(2048), dim3(256), 0, stream,
                       outp, augp, Zf8, R, posdot);

    hipLaunchKernelGGL(gram_kernel, dim3(32, 64), dim3(256), 0, stream,
                       Zf8, R);

    hipLaunchKernelGGL(final_kernel, dim3(1), dim3(256), 0, stream,
                       R, posdot, outf);
}

// Round 16
// 53.138 us; speedup vs baseline: 5.1242x; 1.3684x over previous
//
#include <hip/hip_runtime.h>
#include <hip/hip_bf16.h>

#define NR  8192      // rows per view
#define M   16384     // 2*NR concatenated
#define SUBB 8192     // 64 cols * 128 B (one fp8 Y sub-tile)

constexpr float INV_T   = 2.5f;                  // 1/0.4
constexpr float SCALE_S = 1.89914134f;           // sqrt(2.5*log2(e)); s^2=2.5*log2e
constexpr float E_REFL  = 12.182493960703473f;   // exp(2.5)
constexpr unsigned UNIT_E8M0 = 0x7F7F7F7Fu;      // e8m0 scale = 2^0 in all bytes

typedef int   i32x4 __attribute__((ext_vector_type(4)));
typedef int   i32x8 __attribute__((ext_vector_type(8)));
typedef float f32x4 __attribute__((ext_vector_type(4)));

typedef const __attribute__((address_space(1))) unsigned int* gas_u32;
typedef __attribute__((address_space(3))) unsigned int*       las_u32;

__device__ __forceinline__ float fexp2(float x) {
#if __has_builtin(__builtin_amdgcn_exp2f)
    return __builtin_amdgcn_exp2f(x);
#else
    return exp2f(x);
#endif
}

// Stage one 64-col (8 KB) fp8 sub-tile global->LDS with 256 threads:
// 2 x global_load_lds(16B) per thread. LDS dest linear; global src XOR-pre-
// swizzled (involution on byte bits 4..6 keyed by row&7 = bits 7..9) so
// swizzled 16B fragment reads are low-conflict.
__device__ __forceinline__ void stage_sub8(const char* __restrict__ gsrc,
                                           char* lds, int w, int lane) {
    #pragma unroll
    for (int it = 0; it < 2; ++it) {
        int off = w * 2048 + it * 1024 + lane * 16;
        int swz = off ^ (((off >> 7) & 7) << 4);
        __builtin_amdgcn_global_load_lds((gas_u32)(gsrc + swz),
                                         (las_u32)(lds + w * 2048 + it * 1024),
                                         16, 0, 0);
    }
}

// ---------------------------------------------------------------------------
// Kernel 1: L2-normalize rows; store fp8(e4m3) Z = [z1n; z2n] PRE-SCALED by
// SCALE_S (so the MX-MFMA output is directly the exp2 argument); fp32 cross
// dot; zero the rowsum array R AND the output scalar (final_kernel
// accumulates into it atomically -> must be re-zeroed every call for
// graph-replay determinism).
// ---------------------------------------------------------------------------
__global__ __launch_bounds__(256) void norm_kernel(
    const float* __restrict__ outp, const float* __restrict__ augp,
    unsigned char* __restrict__ Zf8, float* __restrict__ R,
    float* __restrict__ posdot, float* __restrict__ outf)
{
    int gt = blockIdx.x * 256 + threadIdx.x;
    if (gt < M) R[gt] = 0.0f;
    if (gt == 0) outf[0] = 0.0f;

    const int w    = threadIdx.x >> 6;
    const int lane = threadIdx.x & 63;
    const int row  = blockIdx.x * 4 + w;

    float2 a = *(const float2*)(outp + row * 128 + lane * 2);
    float2 b = *(const float2*)(augp + row * 128 + lane * 2);

    float ssa = a.x * a.x + a.y * a.y;
    float ssb = b.x * b.x + b.y * b.y;
    #pragma unroll
    for (int m = 1; m < 64; m <<= 1) {
        ssa += __shfl_xor(ssa, m);
        ssb += __shfl_xor(ssb, m);
    }
    float inva = 1.0f / fmaxf(sqrtf(ssa), 1e-12f);
    float invb = 1.0f / fmaxf(sqrtf(ssb), 1e-12f);

    float xa0 = a.x * inva, xa1 = a.y * inva;   // unit-normalized (fp32)
    float xb0 = b.x * invb, xb1 = b.y * invb;

    unsigned int pa = __builtin_amdgcn_cvt_pk_fp8_f32(xa0 * SCALE_S, xa1 * SCALE_S, 0, false);
    unsigned int pb = __builtin_amdgcn_cvt_pk_fp8_f32(xb0 * SCALE_S, xb1 * SCALE_S, 0, false);
    *(unsigned short*)(Zf8 + (size_t)row * 128 + lane * 2)        = (unsigned short)pa;
    *(unsigned short*)(Zf8 + (size_t)(NR + row) * 128 + lane * 2) = (unsigned short)pb;

    float d = xa0 * xb0 + xa1 * xb1;   // positive-pair dot stays fp32-exact
    #pragma unroll
    for (int m = 1; m < 64; m <<= 1) d += __shfl_xor(d, m);
    if (lane == 0) posdot[row] = d;
}

// ---------------------------------------------------------------------------
// Kernel 2: row sums of exp2(Zs Zs^T) via MX-fp8 K=128 MFMA.
// R12 VERBATIM (best measured: 47.5 us; MfmaUtil 27%, VALUBusy 47%).
// Grid (32 col-chunks, 64 row-blocks) = 2048 blocks; launch_bounds(256,4)
// gives VGPR 44 (no spill — (256,8) capped to 32 VGPR and spilled, R11).
// Block = 256 thr / 4 waves owns 256 rows; wave owns 64 rows (afrag[4],
// full K=128, 32 B/lane, one-time direct-from-L2 read).  Y chunk = 512 cols
// = 8 subtiles of 64 cols (8 KB), double-buffered via global_load_lds.
// Per ct (16 cols): 2 swizzled 16B LDS reads (lane-constant addresses) ->
// b8 -> 4 MFMA (rt) -> 16 exp2 -> 16 adds.  id%8 = ch%8 pins 4 chunks/XCD.
// Overlap-structure variants all failed to beat this (R7 counted-vmcnt
// neutral; R14 single-shot 55; R15 self-paced 56) — wall ~= serial pipe sum
// (MFMA 14.7 + VALU ~20 + LDS ~13 us) is this decomposition's practical
// floor at HIP level.
// ---------------------------------------------------------------------------
__global__ __launch_bounds__(256, 4) void gram_kernel(
    const unsigned char* __restrict__ Zf8, float* __restrict__ R)
{
    __shared__ char buf[2][SUBB];   // 16 KB

    const int tid  = threadIdx.x;
    const int w    = tid >> 6;       // 0..3
    const int lane = tid & 63;
    const int l16  = lane & 15;
    const int lg   = lane >> 4;      // 0..3 (32-byte k-chunk)
    const int ch   = blockIdx.x;     // 0..31 (512 cols each)
    const int rb   = blockIdx.y;     // 0..63 (256 rows each)

    const char* Zb = (const char*)Zf8;
    const char* Xg = Zb + (size_t)rb * 32768;     // 256 rows * 128 B
    const char* Yg = Zb + (size_t)ch * 65536;     // 512 cols * 128 B

    // A fragments: 64 rows per wave, full K=128 (32 B/lane), one-time read
    i32x8 afrag[4];
    #pragma unroll
    for (int rt = 0; rt < 4; ++rt)
        afrag[rt] = *(const i32x8*)(Xg + (w * 64 + rt * 16 + l16) * 128 + lg * 32);

    stage_sub8(Yg, buf[0], w, lane);
    __syncthreads();

    f32x4 rs[4];
    #pragma unroll
    for (int rt = 0; rt < 4; ++rt) rs[rt] = (f32x4){0.f, 0.f, 0.f, 0.f};
    const f32x4 zero4 = (f32x4){0.f, 0.f, 0.f, 0.f};

    // precomputed lane-constant LDS read offsets (ct adds bits >= 11 only)
    const int key   = (l16 & 7) << 4;
    const int lbase = l16 * 128 + lg * 32;
    const int addrA = lbase ^ key;
    const int addrB = (lbase + 16) ^ key;

    #pragma unroll 1
    for (int s = 0; s < 8; ++s) {
        if (s + 1 < 8)
            stage_sub8(Yg + (size_t)(s + 1) * SUBB, buf[(s + 1) & 1], w, lane);

        const char* cur = buf[s & 1];

        #pragma unroll
        for (int ct = 0; ct < 4; ++ct) {
            i32x4 lo = *(const i32x4*)(cur + ct * 2048 + addrA);
            i32x4 hi = *(const i32x4*)(cur + ct * 2048 + addrB);
            i32x8 b8 = {lo[0], lo[1], lo[2], lo[3], hi[0], hi[1], hi[2], hi[3]};
            #pragma unroll
            for (int rt = 0; rt < 4; ++rt) {
                f32x4 d = __builtin_amdgcn_mfma_scale_f32_16x16x128_f8f6f4(
                    afrag[rt], b8, zero4,
                    0 /*fmtA=fp8*/, 0 /*fmtB=fp8*/,
                    0, UNIT_E8M0, 0, UNIT_E8M0);
                f32x4 e;
                e[0] = fexp2(d[0]); e[1] = fexp2(d[1]);
                e[2] = fexp2(d[2]); e[3] = fexp2(d[3]);
                rs[rt] += e;
            }
        }
        __syncthreads();   // stage(s+1) landed + all waves done with cur
    }

    // reduce row sums across the 16 lanes holding one row's columns
    #pragma unroll
    for (int rt = 0; rt < 4; ++rt)
        #pragma unroll
        for (int q = 0; q < 4; ++q) {
            float v = rs[rt][q];
            v += __shfl_xor(v, 1);  v += __shfl_xor(v, 2);
            v += __shfl_xor(v, 4);  v += __shfl_xor(v, 8);
            if (l16 == 0)
                atomicAdd(&R[rb * 256 + w * 64 + rt * 16 + lg * 4 + q], v);
        }
}

// ---------------------------------------------------------------------------
// Kernel 3: loss = mean_i [ -dot_i/tau + 0.5(log(R_i - E) + log(R_{NR+i} - E)) ]
// 32 blocks x 256 thr (1 row/thread), wave-shuffle reduce + one atomicAdd
// per wave into outf (zeroed by norm_kernel each call).  Replaces the
// single-block serial version (64 logf/thread + 9-barrier tree).
// ---------------------------------------------------------------------------
__global__ __launch_bounds__(256) void final_kernel(
    const float* __restrict__ R, const float* __restrict__ posdot,
    float* __restrict__ outv)
{
    const int i = blockIdx.x * 256 + threadIdx.x;   // 0..8191
    float d1 = R[i]      - E_REFL;
    float d2 = R[NR + i] - E_REFL;
    float local = -posdot[i] * INV_T + 0.5f * (logf(d1) + logf(d2));

    #pragma unroll
    for (int m = 1; m < 64; m <<= 1) local += __shfl_xor(local, m);
    if ((threadIdx.x & 63) == 0)
        atomicAdd(outv, local * (1.0f / NR));
}

// ---------------------------------------------------------------------------
extern "C" void kernel_launch(void* const* d_in, const int* in_sizes, int n_in,
                              void* d_out, int out_size, void* d_ws, size_t ws_size,
                              hipStream_t stream) {
    const float* outp = (const float*)d_in[0];
    const float* augp = (const float*)d_in[1];

    char* ws = (char*)d_ws;
    unsigned char* Zf8 = (unsigned char*)ws;                  // 2 MB fp8 [16384][128]
    float* R      = (float*)(ws + 2097152);                   // 16384 f32 row sums
    float* posdot = (float*)(ws + 2097152 + 65536);           // 8192 f32
    float* outf   = (float*)d_out;

    hipLaunchKernelGGL(norm_kernel, dim3(2048), dim3(256), 0, stream,
                       outp, augp, Zf8, R, posdot, outf);

    hipLaunchKernelGGL(gram_kernel, dim3(32, 64), dim3(256), 0, stream,
                       Zf8, R);

    hipLaunchKernelGGL(final_kernel, dim3(32), dim3(256), 0, stream,
                       R, posdot, outf);
}